// Round 15
// baseline (848.775 us; speedup 1.0000x reference)
//
#include <hip/hip_runtime.h>

typedef unsigned short u16;
typedef unsigned int uint;

using f32x4 = __attribute__((ext_vector_type(4))) float;
using bf16x8 = __attribute__((ext_vector_type(8))) __bf16;
using u32x4 = __attribute__((ext_vector_type(4))) uint;

static __device__ __forceinline__ bf16x8 as_bf16x8(uint4 u) {
    union { uint4 a; bf16x8 b; } c; c.a = u; return c.b;
}
static __device__ __forceinline__ bf16x8 as_bf16x8v(u32x4 u) {
    union { u32x4 a; bf16x8 b; } c; c.a = u; return c.b;
}
static __device__ __forceinline__ float bf2f(u16 h) {
    union { uint u; float f; } c; c.u = ((uint)h) << 16; return c.f;
}
static __device__ __forceinline__ u16 f2bf(float f) {
    union { float f; uint u; } c; c.f = f;
    uint u = c.u;
    return (u16)((u + 0x7fffu + ((u >> 16) & 1u)) >> 16);
}
static __device__ __forceinline__ float fast_sigmoid(float x) {
    x = fminf(30.f, fmaxf(-30.f, x));
    return __builtin_amdgcn_rcpf(1.0f + __builtin_amdgcn_exp2f(x * -1.44269504f));
}
static __device__ __forceinline__ float fast_tanh(float x) {
    x = fminf(15.f, fmaxf(-15.f, x));
    return 1.0f - 2.0f * __builtin_amdgcn_rcpf(1.0f + __builtin_amdgcn_exp2f(x * 2.88539008f));
}

static __device__ __forceinline__ u32x4 load_b128_sc0(const u16* p) {
    u32x4 r;
    asm volatile("global_load_dwordx4 %0, %1, off sc0" : "=v"(r) : "v"(p) : "memory");
    return r;
}
static __device__ __forceinline__ void wait_vm0_fence_sched() {
    asm volatile("s_waitcnt vmcnt(0)" ::: "memory");
    __builtin_amdgcn_sched_barrier(0);   // rule #18
}

// constant-index helpers (rule #20)
static __device__ __forceinline__ float vext(f32x4 v, int i) {
    float r = v[0];
    r = (i == 1) ? v[1] : r;
    r = (i == 2) ? v[2] : r;
    r = (i == 3) ? v[3] : r;
    return r;
}
static __device__ __forceinline__ float sel4(float a0, float a1, float a2, float a3, int i) {
    float r = a0;
    r = (i == 1) ? a1 : r;
    r = (i == 2) ? a2 : r;
    r = (i == 3) ? a3 : r;
    return r;
}

static __device__ __forceinline__ int detect_fp32(const uint* w, int nwords) {
    int hits = 0;
    for (int i = 0; i < nwords; ++i) { uint e = (w[i] >> 7) & 0xffu; hits += (e >= 0x80u); }
    return hits > (nwords >> 3);
}
static __device__ __forceinline__ u16 load_bf(const void* p, int i, int fp32) {
    return fp32 ? f2bf(((const float*)p)[i]) : ((const u16*)p)[i];
}

// Fragment-ordered weight pack: wp[((w*KSTEPS + ks)*4 + nt)*512 + lane*8 + j]
__global__ void pack_w(const void* wf, const void* wi, const void* wc, const void* wo,
                       const void* bbf, const void* bbi, const void* bbc, const void* bbo,
                       u16* __restrict__ wp, u16* __restrict__ bp, int K, int KSTEPS) {
    __shared__ int sfp;
    if (threadIdx.x == 0) sfp = detect_fp32((const uint*)wf, 256);
    __syncthreads();
    const int fp32 = sfp;
    int w = blockIdx.x / KSTEPS, ks = blockIdx.x % KSTEPS;
    int nt = threadIdx.x >> 6, lane = threadIdx.x & 63;
    int c16 = lane & 15, q = lane >> 4;
    int n = w * 64 + nt * 16 + c16;
    int u = n >> 2, g = n & 3;
    const void* W = (g == 0) ? wf : (g == 1) ? wi : (g == 2) ? wc : wo;
    union { u16 v[8]; uint4 u4; } tmp;
#pragma unroll
    for (int j = 0; j < 8; ++j) {
        int k = ks * 32 + q * 8 + j;
        tmp.v[j] = (k < K) ? load_bf(W, k * 256 + u, fp32) : (u16)0;
    }
    *(uint4*)(wp + ((w * KSTEPS + ks) * 4 + nt) * 512 + lane * 8) = tmp.u4;
    if (ks == 0 && threadIdx.x < 64) {
        int n2 = w * 64 + threadIdx.x;
        int g2 = n2 & 3;
        const void* B = (g2 == 0) ? bbf : (g2 == 1) ? bbi : (g2 == 2) ? bbc : bbo;
        bp[n2] = load_bf(B, n2 >> 2, fp32);
    }
}

__global__ void pack_misc(const void* emb, const void* w_out, const void* b_out,
                          u16* __restrict__ embp, u16* __restrict__ wob,
                          u16* __restrict__ bob, uint* __restrict__ hzero) {
    __shared__ int sfp;
    if (threadIdx.x == 0) sfp = detect_fp32((const uint*)emb, 256);
    __syncthreads();
    const int fp32 = sfp;
    int gid = blockIdx.x * blockDim.x + threadIdx.x;
    int stride = gridDim.x * blockDim.x;
    for (int i = gid; i < 1000000; i += stride)
        embp[i] = load_bf(emb, i, fp32);
    // zero h1g+h2g (524288 uints) + flags (2ch x 8rg x 64 = 1024 uints)
    for (int i = gid; i < 526336; i += stride) hzero[i] = 0;
    if (blockIdx.x == 0) {
        __shared__ int sfp2;
        if (threadIdx.x == 0) sfp2 = detect_fp32((const uint*)w_out, 128);
        __syncthreads();
        if (threadIdx.x < 256) wob[threadIdx.x] = load_bf(w_out, threadIdx.x, sfp2);
        if (threadIdx.x == 0) bob[0] = load_bf(b_out, 0, sfp2);
    }
}

// Bulk per-WAVE wait (prologue/epilogue only): poll all 16 flags with sc0,
// s_sleep backoff, LLC-atomic safety net (cannot hang).
static __device__ __forceinline__ void wv_wait(uint* grp, uint phase, int lane) {
    const uint* fp = grp + (lane & 15);
    uint* cnt = grp + 32;
    int k = 0;
    while (true) {
        uint v;
        asm volatile("global_load_dword %0, %1, off sc0\n\t"
                     "s_waitcnt vmcnt(0)"
                     : "=v"(v) : "v"(fp) : "memory");
        if (__all((int)(v >= phase))) break;
        __builtin_amdgcn_s_sleep(2);
        if (((++k) & 7) == 0 &&
            __hip_atomic_load(cnt, __ATOMIC_RELAXED,
                              __HIP_MEMORY_SCOPE_AGENT) >= 16u * phase)
            break;
    }
}

// Per-WAVE arrive: drain own stores (vmcnt per-wave), bump LDS counter; the
// last-arriving wave of the half publishes the flag (sc0) + LLC safety add.
static __device__ __forceinline__ void wv_arrive(uint* ldsc_ch, uint* grp, int g,
                                                 uint phase, int lane) {
    asm volatile("s_waitcnt vmcnt(0)" ::: "memory");
    if (lane == 0) {
        uint old = __hip_atomic_fetch_add(ldsc_ch, 1u, __ATOMIC_RELAXED,
                                          __HIP_MEMORY_SCOPE_WORKGROUP);
        if (old == 8u * phase - 1u) {            // last of the 8 waves
            uint* slot = grp + g;
            asm volatile("global_store_dword %0, %1, off sc0"
                         :: "v"(slot), "v"(phase) : "memory");
            __hip_atomic_fetch_add(grp + 32, 1u, __ATOMIC_RELAXED,
                                   __HIP_MEMORY_SCOPE_AGENT);
        }
    }
}

// Persistent-weight LSTM, wave-specialized 2 chains (R14 base), with
// FRAGMENT-GRANULAR dataflow waits: K-fragment ks is produced entirely by
// unit-group blocks {2ks, 2ks+1}, so each fragment is consumed as soon as its
// TWO producers publish — a straggler delays only its 2/16 slice and that
// delay overlaps the other fragments' MFMAs (max-of-16 -> mean-of-16).
// Grid 128 = 8 row-groups (bid&7, XCD-affine) x 16 unit-groups.
// h layout block-major: h[par][ch][rg][g][row:64][ul:16].
#define CSLAB 16384

__global__ void __launch_bounds__(1024, 1)
lstm_kernel(const int* __restrict__ tokens, const u16* __restrict__ embp,
            const u16* __restrict__ wp1, const u16* __restrict__ b1p,
            const u16* __restrict__ wp2, const u16* __restrict__ b2p,
            const u16* __restrict__ wob, const u16* __restrict__ bob,
            u16* __restrict__ h1g, u16* __restrict__ h2g,
            uint* __restrict__ flags, float* __restrict__ out) {
    __shared__ __align__(16) u16 w1s[12 * 4 * 512];   // 49152 B
    __shared__ __align__(16) u16 w2s[16 * 4 * 512];   // 65536 B
    __shared__ uint ldsc[2];                          // per-chain arrival counters
    __shared__ __align__(16) float outscr[1024];      // 4096 B (epilogue)

    const int tid = threadIdx.x;
    const int bid = blockIdx.x;
    const int r2 = bid & 7;                 // row-group (XCD-affine)
    const int g = bid >> 3;                 // unit-group 0..15
    const int gp = g >> 1;                  // own fragment-pair index 0..7
    const int lane = tid & 63;
    const int wv = tid >> 6;                // 0..15
    const int half = wv >> 3;               // chain 0/1
    const int w8 = wv & 7;
    const int nt = w8 & 3;                  // n-tile
    const int mb = (w8 >> 2) * 2;           // m-tiles {mb, mb+1}
    const int c16 = lane & 15, q = lane >> 4;

    const int b = lane & 3;
    const int ulz = nt * 4 + ((lane & 15) >> 2);
    const int gunit = g * 16 + ulz;

    {
        const uint4* s1 = (const uint4*)(wp1 + g * (12 * 4 * 512));
        uint4* d1 = (uint4*)w1s;
        for (int i = tid; i < 3072; i += 1024) d1[i] = s1[i];
        const uint4* s2 = (const uint4*)(wp2 + g * (16 * 4 * 512));
        uint4* d2 = (uint4*)w2s;
        for (int i = tid; i < 4096; i += 1024) d2[i] = s2[i];
        if (tid < 2) ldsc[tid] = 0u;
    }
    ushort4 bl1 = *(const ushort4*)(b1p + gunit * 4);
    ushort4 bl2 = *(const ushort4*)(b2p + gunit * 4);
    const float b1f = bf2f(bl1.x), b1i = bf2f(bl1.y), b1c = bf2f(bl1.z), b1o = bf2f(bl1.w);
    const float b2f = bf2f(bl2.x), b2i = bf2f(bl2.y), b2c = bf2f(bl2.z), b2o = bf2f(bl2.w);
    float c1a = 0.f, c1b = 0.f, c2a = 0.f, c2b = 0.f;
    uint* fg = flags + (half * 8 + r2) * 64;
    uint* lc = &ldsc[half];
    __syncthreads();                        // weights + counters ready

    const u16* bp1 = w1s + nt * 512 + lane * 8;
    const u16* bp2 = w2s + nt * 512 + lane * 8;

    ushort4 xlo[4], xhi[4];
#define LOAD_X(m, t)                                                           \
    {                                                                          \
        int row = r2 * 128 + half * 64 + (m) * 16 + c16;                       \
        int tok = tokens[row * 80 + (t)];                                      \
        const u16* xb = embp + tok * 100 + q * 8;                              \
        _Pragma("unroll")                                                      \
        for (int k2 = 0; k2 < 4; ++k2) {                                       \
            xlo[k2] = *(const ushort4*)(xb + k2 * 32);                         \
            xhi[k2] = *(const ushort4*)(xb + k2 * 32 + 4);                     \
        }                                                                      \
    }
#define XFRAG(k2) ({ union { ushort4 a[2]; bf16x8 v; } xu;                     \
                     xu.a[0] = xlo[k2]; xu.a[1] = xhi[k2]; xu.v; })

#define GATES(accv, B0, B1, B2, B3, cref, hout)                                \
    {                                                                          \
        float v0 = vext(accv, b);                                              \
        float v1 = __shfl_xor(vext(accv, b ^ 1), 1, 64);                       \
        float v2 = __shfl_xor(vext(accv, b ^ 2), 2, 64);                       \
        float v3 = __shfl_xor(vext(accv, b ^ 3), 3, 64);                       \
        float zf = sel4(v0, v1, v2, v3, b);                                    \
        float zi = sel4(v0, v1, v2, v3, b ^ 1);                                \
        float zc = sel4(v0, v1, v2, v3, b ^ 2);                                \
        float zo = sel4(v0, v1, v2, v3, b ^ 3);                                \
        float gf = fast_sigmoid(zf + B0);                                      \
        float gi = fast_sigmoid(zi + B1);                                      \
        float gc = fast_tanh(zc + B2);                                         \
        float go = fast_sigmoid(zo + B3);                                      \
        float cn = gf * cref + gi * gc;                                        \
        cref = cn;                                                             \
        hout = f2bf(go * fast_tanh(cn));                                       \
    }

// Fragment readiness wait: skip if both producer bits already in rmask; else
// wave-wide poll (lane<16 reads flag[lane]) rebuilds the mask. s_sleep(1)
// backoff; LLC-atomic safety net every 16 polls (counter>=16*phase => all
// producers published => full mask). Cannot hang.
#define FRAG_WAIT(ksp, ph)                                                     \
    if (((rmask >> (2 * (ksp))) & 3u) != 3u) {                                 \
        const uint* fpp = fg + (lane & 15);                                    \
        uint* cntp = fg + 32;                                                  \
        int kk = 0;                                                            \
        while (true) {                                                         \
            uint v;                                                            \
            asm volatile("global_load_dword %0, %1, off sc0\n\t"               \
                         "s_waitcnt vmcnt(0)"                                  \
                         : "=v"(v) : "v"(fpp) : "memory");                     \
            unsigned long long bl = __ballot((int)(v >= (ph)));                \
            rmask = (uint)(bl & 0xffffull);                                    \
            if (((rmask >> (2 * (ksp))) & 3u) == 3u) break;                    \
            __builtin_amdgcn_s_sleep(1);                                       \
            if (((++kk) & 15) == 0 &&                                          \
                __hip_atomic_load(cntp, __ATOMIC_RELAXED,                      \
                                  __HIP_MEMORY_SCOPE_AGENT) >= 16u * (ph)) {   \
                rmask = 0xffffu;                                               \
                break;                                                         \
            }                                                                  \
        }                                                                      \
    }

// One fragment step (J compile-time via unroll): prefetch next fragment's 4
// loads behind a counted vmcnt(4), then 6 MFMAs on the current fragment.
#define FRAG_STEP(J)                                                           \
    {                                                                          \
        u32x4 n2a = f2a, n1a = f1a, n2b = f2b, n1b = f1b;                      \
        if ((J) < 7) {                                                         \
            int kspn = (gp + (J) + 1) & 7;                                     \
            FRAG_WAIT(kspn, phase);                                            \
            const u16* h2fn = h2base + kspn * 2048;                            \
            const u16* h1fn = h1base + kspn * 2048;                            \
            n2a = load_b128_sc0(h2fn + loffA);                                 \
            n1a = load_b128_sc0(h1fn + loffA);                                 \
            n2b = load_b128_sc0(h2fn + loffB);                                 \
            n1b = load_b128_sc0(h1fn + loffB);                                 \
            asm volatile("s_waitcnt vmcnt(4)" ::: "memory");                   \
        } else {                                                               \
            asm volatile("s_waitcnt vmcnt(0)" ::: "memory");                   \
        }                                                                      \
        __builtin_amdgcn_sched_barrier(0);                                     \
        int kspc = (gp + (J)) & 7;                                             \
        const uint4 w2lo = *(const uint4*)(bp2 + kspc * 2048);                 \
        const uint4 w2hi = *(const uint4*)(bp2 + (8 + kspc) * 2048);           \
        const uint4 w1lo = *(const uint4*)(bp1 + kspc * 2048);                 \
        acc2a = __builtin_amdgcn_mfma_f32_16x16x32_bf16(as_bf16x8v(f2a), as_bf16x8(w2lo), acc2a, 0, 0, 0); \
        acc1a = __builtin_amdgcn_mfma_f32_16x16x32_bf16(as_bf16x8v(f1a), as_bf16x8(w1lo), acc1a, 0, 0, 0); \
        acc2a = __builtin_amdgcn_mfma_f32_16x16x32_bf16(as_bf16x8v(f1a), as_bf16x8(w2hi), acc2a, 0, 0, 0); \
        acc2b = __builtin_amdgcn_mfma_f32_16x16x32_bf16(as_bf16x8v(f2b), as_bf16x8(w2lo), acc2b, 0, 0, 0); \
        acc1b = __builtin_amdgcn_mfma_f32_16x16x32_bf16(as_bf16x8v(f1b), as_bf16x8(w1lo), acc1b, 0, 0, 0); \
        acc2b = __builtin_amdgcn_mfma_f32_16x16x32_bf16(as_bf16x8v(f1b), as_bf16x8(w2hi), acc2b, 0, 0, 0); \
        f2a = n2a; f1a = n1a; f2b = n2b; f1b = n1b;                            \
    }

    // ---- prologue: h1(0) (x-only) for both m-tiles, publish phase 1 ----
    {
        LOAD_X(mb, 0);
        f32x4 acc = (f32x4){0.f, 0.f, 0.f, 0.f};
#pragma unroll
        for (int k2 = 0; k2 < 4; ++k2)
            acc = __builtin_amdgcn_mfma_f32_16x16x32_bf16(
                XFRAG(k2), as_bf16x8(*(const uint4*)(bp1 + (8 + k2) * 2048)), acc, 0, 0, 0);
        u16 h1o;
        GATES(acc, b1f, b1i, b1c, b1o, c1a, h1o);
        h1g[((0 * 2 + half) * 8 + r2) * CSLAB + g * 1024 + (mb * 16 + q * 4 + b) * 16 + ulz] = h1o;
        LOAD_X(mb + 1, 0);
        f32x4 accB = (f32x4){0.f, 0.f, 0.f, 0.f};
#pragma unroll
        for (int k2 = 0; k2 < 4; ++k2)
            accB = __builtin_amdgcn_mfma_f32_16x16x32_bf16(
                XFRAG(k2), as_bf16x8(*(const uint4*)(bp1 + (8 + k2) * 2048)), accB, 0, 0, 0);
        u16 h1oB;
        GATES(accB, b1f, b1i, b1c, b1o, c1b, h1oB);
        h1g[((0 * 2 + half) * 8 + r2) * CSLAB + g * 1024 + ((mb + 1) * 16 + q * 4 + b) * 16 + ulz] = h1oB;
        wv_arrive(lc, fg, g, 1u, lane);
    }

    // ---- main loop: per wave, own chain only; fragment-granular waits ----
#pragma unroll 1
    for (int i = 0; i < 79; ++i) {
        const int p_h2r = (i + 1) & 1, p_h1r = i & 1;
        const int p_h2w = i & 1, p_h1w = (i + 1) & 1;

        // pre-wait: x gather + x-partials of z1(i+1) for both m-tiles
        LOAD_X(mb, i + 1);
        f32x4 acc1a = (f32x4){0.f, 0.f, 0.f, 0.f};
#pragma unroll
        for (int k2 = 0; k2 < 4; ++k2)
            acc1a = __builtin_amdgcn_mfma_f32_16x16x32_bf16(
                XFRAG(k2), as_bf16x8(*(const uint4*)(bp1 + (8 + k2) * 2048)), acc1a, 0, 0, 0);
        LOAD_X(mb + 1, i + 1);
        f32x4 acc1b = (f32x4){0.f, 0.f, 0.f, 0.f};
#pragma unroll
        for (int k2 = 0; k2 < 4; ++k2)
            acc1b = __builtin_amdgcn_mfma_f32_16x16x32_bf16(
                XFRAG(k2), as_bf16x8(*(const uint4*)(bp1 + (8 + k2) * 2048)), acc1b, 0, 0, 0);

        const uint phase = (uint)(i + 1);
        const u16* h2base = h2g + ((p_h2r * 2 + half) * 8 + r2) * CSLAB;
        const u16* h1base = h1g + ((p_h1r * 2 + half) * 8 + r2) * CSLAB;
        const int loffA = (q >> 1) * 1024 + (mb * 16 + c16) * 16 + (q & 1) * 8;
        const int loffB = loffA + 256;   // (mb+1) is 16 rows later
        f32x4 acc2a = (f32x4){0.f, 0.f, 0.f, 0.f};
        f32x4 acc2b = (f32x4){0.f, 0.f, 0.f, 0.f};
        uint rmask = 0u;

        // first fragment (own pair — earliest ready): wait + 4 loads
        FRAG_WAIT(gp, phase);
        const u16* h2f0 = h2base + gp * 2048;
        const u16* h1f0 = h1base + gp * 2048;
        u32x4 f2a = load_b128_sc0(h2f0 + loffA);
        u32x4 f1a = load_b128_sc0(h1f0 + loffA);
        u32x4 f2b = load_b128_sc0(h2f0 + loffB);
        u32x4 f1b = load_b128_sc0(h1f0 + loffB);

        __builtin_amdgcn_s_setprio(1);
        FRAG_STEP(0) FRAG_STEP(1) FRAG_STEP(2) FRAG_STEP(3)
        FRAG_STEP(4) FRAG_STEP(5) FRAG_STEP(6) FRAG_STEP(7)

        u16 h2oA, h1oA, h2oB, h1oB;
        GATES(acc2a, b2f, b2i, b2c, b2o, c2a, h2oA);
        GATES(acc1a, b1f, b1i, b1c, b1o, c1a, h1oA);
        GATES(acc2b, b2f, b2i, b2c, b2o, c2b, h2oB);
        GATES(acc1b, b1f, b1i, b1c, b1o, c1b, h1oB);
        const int hidxA = g * 1024 + (mb * 16 + q * 4 + b) * 16 + ulz;
        const int hidxB = hidxA + 256;
        h2g[((p_h2w * 2 + half) * 8 + r2) * CSLAB + hidxA] = h2oA;
        h1g[((p_h1w * 2 + half) * 8 + r2) * CSLAB + hidxA] = h1oA;
        h2g[((p_h2w * 2 + half) * 8 + r2) * CSLAB + hidxB] = h2oB;
        h1g[((p_h1w * 2 + half) * 8 + r2) * CSLAB + hidxB] = h1oB;
        __builtin_amdgcn_s_setprio(0);

        wv_arrive(lc, fg, g, (uint)(i + 2), lane);   // publish h2(i), h1(i+1)
    }

    // ---- epilogue: z2(79) for both m-tiles (bulk wait, once) ----
    {
        wv_wait(fg, 80u, lane);               // h2(78) par0, h1(79) par1
#pragma unroll 1
        for (int s = 0; s < 2; ++s) {
            const int m = mb + s;
            const int loffm = (q >> 1) * 1024 + (m * 16 + c16) * 16 + (q & 1) * 8;
            const int hidxm = g * 1024 + (m * 16 + q * 4 + b) * 16 + ulz;
            const u16* h2b = h2g + ((0 * 2 + half) * 8 + r2) * CSLAB + loffm;
            const u16* h1b = h1g + ((1 * 2 + half) * 8 + r2) * CSLAB + loffm;
            u32x4 ag2[8], ag1[8];
#pragma unroll
            for (int ks = 0; ks < 8; ++ks) ag2[ks] = load_b128_sc0(h2b + ks * 2048);
#pragma unroll
            for (int ks = 0; ks < 8; ++ks) ag1[ks] = load_b128_sc0(h1b + ks * 2048);
            wait_vm0_fence_sched();
            f32x4 acc2 = (f32x4){0.f, 0.f, 0.f, 0.f};
#pragma unroll
            for (int ks = 0; ks < 8; ++ks)
                acc2 = __builtin_amdgcn_mfma_f32_16x16x32_bf16(
                    as_bf16x8v(ag2[ks]), as_bf16x8(*(const uint4*)(bp2 + ks * 2048)), acc2, 0, 0, 0);
#pragma unroll
            for (int ks = 0; ks < 8; ++ks)
                acc2 = __builtin_amdgcn_mfma_f32_16x16x32_bf16(
                    as_bf16x8v(ag1[ks]), as_bf16x8(*(const uint4*)(bp2 + (8 + ks) * 2048)), acc2, 0, 0, 0);
            u16 h2o;
            if (s == 0) { GATES(acc2, b2f, b2i, b2c, b2o, c2a, h2o); }
            else        { GATES(acc2, b2f, b2i, b2c, b2o, c2b, h2o); }
            h2g[((1 * 2 + half) * 8 + r2) * CSLAB + hidxm] = h2o;   // h2(79) par1
        }
        wv_arrive(lc, fg, g, 81u, lane);
        wv_wait(fg, 81u, lane);
    }
    __syncthreads();   // join halves before output

    // ---- output: sigmoid(h2 @ w_out + b_out) by g==0 blocks ----
    if (g == 0) {
#pragma unroll 1
        for (int ch = 0; ch < 2; ++ch) {
            const u16* base = h2g + ((1 * 2 + ch) * 8 + r2) * CSLAB;
            int rr = tid >> 4, s = tid & 15;
            const u16* hp = base + s * 1024 + rr * 16;
            u32x4 hv0 = load_b128_sc0(hp);
            u32x4 hv1 = load_b128_sc0(hp + 8);
            wait_vm0_fence_sched();
            const u16* wq = wob + s * 16;
            union { u32x4 v[2]; u16 h[16]; } hu; hu.v[0] = hv0; hu.v[1] = hv1;
            float dot = 0.f;
#pragma unroll
            for (int k = 0; k < 16; ++k) dot += bf2f(hu.h[k]) * bf2f(wq[k]);
            __syncthreads();
            outscr[rr * 16 + s] = dot;
            __syncthreads();
            if (tid < 64) {
                float ssum = 0.f;
                for (int k = 0; k < 16; ++k) ssum += outscr[tid * 16 + k];
                out[r2 * 128 + ch * 64 + tid] = fast_sigmoid(ssum + bf2f(bob[0]));
            }
        }
    }
}

extern "C" void kernel_launch(void* const* d_in, const int* in_sizes, int n_in,
                              void* d_out, int out_size, void* d_ws, size_t ws_size,
                              hipStream_t stream) {
    const int* tokens = (const int*)d_in[0];
    const void* emb = d_in[1];
    const void* wf1 = d_in[2];  const void* bf1_ = d_in[3];
    const void* wi1 = d_in[4];  const void* bi1_ = d_in[5];
    const void* wc1 = d_in[6];  const void* bc1_ = d_in[7];
    const void* wo1 = d_in[8];  const void* bo1_ = d_in[9];
    const void* wf2 = d_in[10]; const void* bf2_ = d_in[11];
    const void* wi2 = d_in[12]; const void* bi2_ = d_in[13];
    const void* wc2 = d_in[14]; const void* bc2_ = d_in[15];
    const void* wo2 = d_in[16]; const void* bo2_ = d_in[17];
    const void* w_out = d_in[18];
    const void* b_out = d_in[19];

    u16* wp1 = (u16*)d_ws;                 // 393216
    u16* wp2 = wp1 + 16 * 12 * 4 * 512;    // 524288
    u16* b1p = wp2 + 16 * 16 * 4 * 512;    // 1024
    u16* b2p = b1p + 1024;                 // 1024
    u16* wob = b2p + 1024;                 // 256
    u16* bob = wob + 256;                  // 8 (pad)
    u16* embp = bob + 8;                   // 1,000,000 (16B-aligned)
    u16* h1g = embp + 1000000;             // 2par x 2ch x 8rg x 16384 = 524288
    u16* h2g = h1g + 524288;               // same
    uint* flags = (uint*)(h2g + 524288);   // 2ch x 8rg x 64 uints

    pack_w<<<dim3(16 * 12), dim3(256), 0, stream>>>(wf1, wi1, wc1, wo1, bf1_, bi1_, bc1_, bo1_,
                                                    wp1, b1p, 356, 12);
    pack_w<<<dim3(16 * 16), dim3(256), 0, stream>>>(wf2, wi2, wc2, wo2, bf2_, bi2_, bc2_, bo2_,
                                                    wp2, b2p, 512, 16);
    pack_misc<<<dim3(512), dim3(256), 0, stream>>>(emb, w_out, b_out, embp, wob, bob, (uint*)h1g);
    lstm_kernel<<<dim3(128), dim3(1024), 0, stream>>>(tokens, embp, wp1, b1p, wp2, b2p,
                                                      wob, bob, h1g, h2g, flags, (float*)d_out);
}

// Round 16
// 767.697 us; speedup vs baseline: 1.1056x; 1.1056x over previous
//
#include <hip/hip_runtime.h>

typedef unsigned short u16;
typedef unsigned int uint;

using f32x4 = __attribute__((ext_vector_type(4))) float;
using bf16x8 = __attribute__((ext_vector_type(8))) __bf16;
using u32x4 = __attribute__((ext_vector_type(4))) uint;

static __device__ __forceinline__ bf16x8 as_bf16x8(uint4 u) {
    union { uint4 a; bf16x8 b; } c; c.a = u; return c.b;
}
static __device__ __forceinline__ bf16x8 as_bf16x8v(u32x4 u) {
    union { u32x4 a; bf16x8 b; } c; c.a = u; return c.b;
}
static __device__ __forceinline__ float bf2f(u16 h) {
    union { uint u; float f; } c; c.u = ((uint)h) << 16; return c.f;
}
static __device__ __forceinline__ u16 f2bf(float f) {
    union { float f; uint u; } c; c.f = f;
    uint u = c.u;
    return (u16)((u + 0x7fffu + ((u >> 16) & 1u)) >> 16);
}
static __device__ __forceinline__ float fast_sigmoid(float x) {
    x = fminf(30.f, fmaxf(-30.f, x));
    return __builtin_amdgcn_rcpf(1.0f + __builtin_amdgcn_exp2f(x * -1.44269504f));
}
static __device__ __forceinline__ float fast_tanh(float x) {
    x = fminf(15.f, fmaxf(-15.f, x));
    return 1.0f - 2.0f * __builtin_amdgcn_rcpf(1.0f + __builtin_amdgcn_exp2f(x * 2.88539008f));
}

static __device__ __forceinline__ u32x4 load_b128_sc0(const u16* p) {
    u32x4 r;
    asm volatile("global_load_dwordx4 %0, %1, off sc0" : "=v"(r) : "v"(p) : "memory");
    return r;
}
static __device__ __forceinline__ void wait_vm0_fence_sched() {
    asm volatile("s_waitcnt vmcnt(0)" ::: "memory");
    __builtin_amdgcn_sched_barrier(0);   // rule #18
}

// constant-index helpers (rule #20)
static __device__ __forceinline__ float vext(f32x4 v, int i) {
    float r = v[0];
    r = (i == 1) ? v[1] : r;
    r = (i == 2) ? v[2] : r;
    r = (i == 3) ? v[3] : r;
    return r;
}
static __device__ __forceinline__ float sel4(float a0, float a1, float a2, float a3, int i) {
    float r = a0;
    r = (i == 1) ? a1 : r;
    r = (i == 2) ? a2 : r;
    r = (i == 3) ? a3 : r;
    return r;
}

static __device__ __forceinline__ int detect_fp32(const uint* w, int nwords) {
    int hits = 0;
    for (int i = 0; i < nwords; ++i) { uint e = (w[i] >> 7) & 0xffu; hits += (e >= 0x80u); }
    return hits > (nwords >> 3);
}
static __device__ __forceinline__ u16 load_bf(const void* p, int i, int fp32) {
    return fp32 ? f2bf(((const float*)p)[i]) : ((const u16*)p)[i];
}

// Fragment-ordered weight pack: wp[((w*KSTEPS + ks)*4 + nt)*512 + lane*8 + j]
__global__ void pack_w(const void* wf, const void* wi, const void* wc, const void* wo,
                       const void* bbf, const void* bbi, const void* bbc, const void* bbo,
                       u16* __restrict__ wp, u16* __restrict__ bp, int K, int KSTEPS) {
    __shared__ int sfp;
    if (threadIdx.x == 0) sfp = detect_fp32((const uint*)wf, 256);
    __syncthreads();
    const int fp32 = sfp;
    int w = blockIdx.x / KSTEPS, ks = blockIdx.x % KSTEPS;
    int nt = threadIdx.x >> 6, lane = threadIdx.x & 63;
    int c16 = lane & 15, q = lane >> 4;
    int n = w * 64 + nt * 16 + c16;
    int u = n >> 2, g = n & 3;
    const void* W = (g == 0) ? wf : (g == 1) ? wi : (g == 2) ? wc : wo;
    union { u16 v[8]; uint4 u4; } tmp;
#pragma unroll
    for (int j = 0; j < 8; ++j) {
        int k = ks * 32 + q * 8 + j;
        tmp.v[j] = (k < K) ? load_bf(W, k * 256 + u, fp32) : (u16)0;
    }
    *(uint4*)(wp + ((w * KSTEPS + ks) * 4 + nt) * 512 + lane * 8) = tmp.u4;
    if (ks == 0 && threadIdx.x < 64) {
        int n2 = w * 64 + threadIdx.x;
        int g2 = n2 & 3;
        const void* B = (g2 == 0) ? bbf : (g2 == 1) ? bbi : (g2 == 2) ? bbc : bbo;
        bp[n2] = load_bf(B, n2 >> 2, fp32);
    }
}

__global__ void pack_misc(const void* emb, const void* w_out, const void* b_out,
                          u16* __restrict__ embp, u16* __restrict__ wob,
                          u16* __restrict__ bob, uint* __restrict__ hzero) {
    __shared__ int sfp;
    if (threadIdx.x == 0) sfp = detect_fp32((const uint*)emb, 256);
    __syncthreads();
    const int fp32 = sfp;
    int gid = blockIdx.x * blockDim.x + threadIdx.x;
    int stride = gridDim.x * blockDim.x;
    for (int i = gid; i < 1000000; i += stride)
        embp[i] = load_bf(emb, i, fp32);
    // zero h1g+h2g (524288 uints) + flags (4ch x 8rg x 64 = 2048 uints)
    for (int i = gid; i < 526336; i += stride) hzero[i] = 0;
    if (blockIdx.x == 0) {
        __shared__ int sfp2;
        if (threadIdx.x == 0) sfp2 = detect_fp32((const uint*)w_out, 128);
        __syncthreads();
        if (threadIdx.x < 256) wob[threadIdx.x] = load_bf(w_out, threadIdx.x, sfp2);
        if (threadIdx.x == 0) bob[0] = load_bf(b_out, 0, sfp2);
    }
}

// Per-WAVE wait with s_sleep backoff: a sleeping wave is removed from issue
// arbitration, so pollers consume ~zero SIMD issue slots while sibling
// chains' waves compute. LLC-atomic safety net every 8th poll (cannot hang).
static __device__ __forceinline__ void wv_wait(uint* grp, uint phase, int lane) {
    const uint* fp = grp + (lane & 15);
    uint* cnt = grp + 32;
    int k = 0;
    while (true) {
        uint v;
        asm volatile("global_load_dword %0, %1, off sc0\n\t"
                     "s_waitcnt vmcnt(0)"
                     : "=v"(v) : "v"(fp) : "memory");
        if (__all((int)(v >= phase))) break;
        __builtin_amdgcn_s_sleep(2);          // yield issue slots to compute waves
        if (((++k) & 7) == 0 &&
            __hip_atomic_load(cnt, __ATOMIC_RELAXED,
                              __HIP_MEMORY_SCOPE_AGENT) >= 16u * phase)
            break;
    }
}

// Per-WAVE arrive: drain own stores (vmcnt per-wave), bump LDS counter; the
// LAST of the chain's 4 waves publishes the flag (sc0) + LLC safety add.
static __device__ __forceinline__ void wv_arrive(uint* ldsc_ch, uint* grp, int g,
                                                 uint phase, int lane) {
    asm volatile("s_waitcnt vmcnt(0)" ::: "memory");
    if (lane == 0) {
        uint old = __hip_atomic_fetch_add(ldsc_ch, 1u, __ATOMIC_RELAXED,
                                          __HIP_MEMORY_SCOPE_WORKGROUP);
        if (old == 4u * phase - 1u) {            // last of the 4 waves
            uint* slot = grp + g;
            asm volatile("global_store_dword %0, %1, off sc0"
                         :: "v"(slot), "v"(phase) : "memory");
            __hip_atomic_fetch_add(grp + 32, 1u, __ATOMIC_RELAXED,
                                   __HIP_MEMORY_SCOPE_AGENT);
        }
    }
}

// Persistent-weight LSTM, FOUR wave-specialized chains WITH sleep-yield +
// setprio (completes the chain-count x wait-mechanism matrix; R13's 4-chain
// failure was hot-spin starvation, fixed in R14). chain = wv>>2: each SIMD
// hosts one wave of each chain, so a waiting chain's exchange latency is
// hidden by THREE sibling chains' compute. Zero block-wide barriers in loop.
// Grid 128 = 8 row-groups (bid&7, XCD-affine) x 16 unit-groups.
// h layout block-major: h[par][ch][rg][g][row:32][ul:16].
#define CSLAB 8192

__global__ void __launch_bounds__(1024, 1)
lstm_kernel(const int* __restrict__ tokens, const u16* __restrict__ embp,
            const u16* __restrict__ wp1, const u16* __restrict__ b1p,
            const u16* __restrict__ wp2, const u16* __restrict__ b2p,
            const u16* __restrict__ wob, const u16* __restrict__ bob,
            u16* __restrict__ h1g, u16* __restrict__ h2g,
            uint* __restrict__ flags, float* __restrict__ out) {
    __shared__ __align__(16) u16 w1s[12 * 4 * 512];   // 49152 B
    __shared__ __align__(16) u16 w2s[16 * 4 * 512];   // 65536 B
    __shared__ uint ldsc[4];                          // per-chain arrival counters
    __shared__ __align__(16) float outscr[512];       // 2048 B (epilogue)

    const int tid = threadIdx.x;
    const int bid = blockIdx.x;
    const int r2 = bid & 7;                 // row-group (XCD-affine)
    const int g = bid >> 3;                 // unit-group 0..15
    const int lane = tid & 63;
    const int wv = tid >> 6;                // 0..15
    const int ch = wv >> 2;                 // chain 0..3 (one wave per SIMD each)
    const int nt = wv & 3;                  // n-tile
    const int c16 = lane & 15, q = lane >> 4;

    const int b = lane & 3;
    const int ulz = nt * 4 + ((lane & 15) >> 2);
    const int gunit = g * 16 + ulz;

    {
        const uint4* s1 = (const uint4*)(wp1 + g * (12 * 4 * 512));
        uint4* d1 = (uint4*)w1s;
        for (int i = tid; i < 3072; i += 1024) d1[i] = s1[i];
        const uint4* s2 = (const uint4*)(wp2 + g * (16 * 4 * 512));
        uint4* d2 = (uint4*)w2s;
        for (int i = tid; i < 4096; i += 1024) d2[i] = s2[i];
        if (tid < 4) ldsc[tid] = 0u;
    }
    ushort4 bl1 = *(const ushort4*)(b1p + gunit * 4);
    ushort4 bl2 = *(const ushort4*)(b2p + gunit * 4);
    const float b1f = bf2f(bl1.x), b1i = bf2f(bl1.y), b1c = bf2f(bl1.z), b1o = bf2f(bl1.w);
    const float b2f = bf2f(bl2.x), b2i = bf2f(bl2.y), b2c = bf2f(bl2.z), b2o = bf2f(bl2.w);
    float c1a = 0.f, c1b = 0.f, c2a = 0.f, c2b = 0.f;   // m0/m1 cell states
    uint* fg = flags + (ch * 8 + r2) * 64;
    uint* lc = &ldsc[ch];
    __syncthreads();                        // weights + counters ready

    const u16* bp1 = w1s + nt * 512 + lane * 8;
    const u16* bp2 = w2s + nt * 512 + lane * 8;

    ushort4 xlo[4], xhi[4];
#define LOAD_X(m, t)                                                           \
    {                                                                          \
        int row = r2 * 128 + ch * 32 + (m) * 16 + c16;                         \
        int tok = tokens[row * 80 + (t)];                                      \
        const u16* xb = embp + tok * 100 + q * 8;                              \
        _Pragma("unroll")                                                      \
        for (int k2 = 0; k2 < 4; ++k2) {                                       \
            xlo[k2] = *(const ushort4*)(xb + k2 * 32);                         \
            xhi[k2] = *(const ushort4*)(xb + k2 * 32 + 4);                     \
        }                                                                      \
    }
#define XFRAG(k2) ({ union { ushort4 a[2]; bf16x8 v; } xu;                     \
                     xu.a[0] = xlo[k2]; xu.a[1] = xhi[k2]; xu.v; })

#define GATES(accv, B0, B1, B2, B3, cref, hout)                                \
    {                                                                          \
        float v0 = vext(accv, b);                                              \
        float v1 = __shfl_xor(vext(accv, b ^ 1), 1, 64);                       \
        float v2 = __shfl_xor(vext(accv, b ^ 2), 2, 64);                       \
        float v3 = __shfl_xor(vext(accv, b ^ 3), 3, 64);                       \
        float zf = sel4(v0, v1, v2, v3, b);                                    \
        float zi = sel4(v0, v1, v2, v3, b ^ 1);                                \
        float zc = sel4(v0, v1, v2, v3, b ^ 2);                                \
        float zo = sel4(v0, v1, v2, v3, b ^ 3);                                \
        float gf = fast_sigmoid(zf + B0);                                      \
        float gi = fast_sigmoid(zi + B1);                                      \
        float gc = fast_tanh(zc + B2);                                         \
        float go = fast_sigmoid(zo + B3);                                      \
        float cn = gf * cref + gi * gc;                                        \
        cref = cn;                                                             \
        hout = f2bf(go * fast_tanh(cn));                                       \
    }

// one m-sub of one chain-step: z2(i) (K=512) + finish z1(i+1) (h1-part),
// gates, scattered u16 stores (R14 scheme). acc1 carries the pre-wait
// x-partial.
#define MSUB(m, acc1, c1ref, c2ref, p2r, p1r, p2w, p1w)                        \
    {                                                                          \
        const int loffm = (q >> 1) * 512 + ((m) * 16 + c16) * 16 + (q & 1) * 8; \
        const int hidxm = g * 512 + ((m) * 16 + q * 4 + b) * 16 + ulz;         \
        const u16* h2b = h2g + (((p2r) * 4 + ch) * 8 + r2) * CSLAB + loffm;    \
        const u16* h1b = h1g + (((p1r) * 4 + ch) * 8 + r2) * CSLAB + loffm;    \
        u32x4 ag2[8], ag1[8];                                                  \
        _Pragma("unroll")                                                      \
        for (int ks = 0; ks < 8; ++ks) ag2[ks] = load_b128_sc0(h2b + ks * 1024); \
        _Pragma("unroll")                                                      \
        for (int ks = 0; ks < 8; ++ks) ag1[ks] = load_b128_sc0(h1b + ks * 1024); \
        wait_vm0_fence_sched();                                                \
        f32x4 acc2 = (f32x4){0.f, 0.f, 0.f, 0.f};                              \
        _Pragma("unroll")                                                      \
        for (int ks = 0; ks < 8; ++ks)                                         \
            acc2 = __builtin_amdgcn_mfma_f32_16x16x32_bf16(                    \
                as_bf16x8v(ag2[ks]), as_bf16x8(*(const uint4*)(bp2 + ks * 2048)), acc2, 0, 0, 0); \
        _Pragma("unroll")                                                      \
        for (int ks = 0; ks < 8; ++ks)                                         \
            acc2 = __builtin_amdgcn_mfma_f32_16x16x32_bf16(                    \
                as_bf16x8v(ag1[ks]), as_bf16x8(*(const uint4*)(bp2 + (8 + ks) * 2048)), acc2, 0, 0, 0); \
        _Pragma("unroll")                                                      \
        for (int ks = 0; ks < 8; ++ks)                                         \
            acc1 = __builtin_amdgcn_mfma_f32_16x16x32_bf16(                    \
                as_bf16x8v(ag1[ks]), as_bf16x8(*(const uint4*)(bp1 + ks * 2048)), acc1, 0, 0, 0); \
        u16 h2o, h1o;                                                          \
        GATES(acc2, b2f, b2i, b2c, b2o, c2ref, h2o);                           \
        GATES(acc1, b1f, b1i, b1c, b1o, c1ref, h1o);                           \
        h2g[(((p2w) * 4 + ch) * 8 + r2) * CSLAB + hidxm] = h2o;                \
        h1g[(((p1w) * 4 + ch) * 8 + r2) * CSLAB + hidxm] = h1o;                \
    }

    // ---- prologue: h1(0) (x-only) for both m-tiles, publish phase 1 ----
    {
        LOAD_X(0, 0);
        f32x4 acc = (f32x4){0.f, 0.f, 0.f, 0.f};
#pragma unroll
        for (int k2 = 0; k2 < 4; ++k2)
            acc = __builtin_amdgcn_mfma_f32_16x16x32_bf16(
                XFRAG(k2), as_bf16x8(*(const uint4*)(bp1 + (8 + k2) * 2048)), acc, 0, 0, 0);
        u16 h1o;
        GATES(acc, b1f, b1i, b1c, b1o, c1a, h1o);
        h1g[((0 * 4 + ch) * 8 + r2) * CSLAB + g * 512 + (0 * 16 + q * 4 + b) * 16 + ulz] = h1o;
        LOAD_X(1, 0);
        f32x4 accB = (f32x4){0.f, 0.f, 0.f, 0.f};
#pragma unroll
        for (int k2 = 0; k2 < 4; ++k2)
            accB = __builtin_amdgcn_mfma_f32_16x16x32_bf16(
                XFRAG(k2), as_bf16x8(*(const uint4*)(bp1 + (8 + k2) * 2048)), accB, 0, 0, 0);
        u16 h1oB;
        GATES(accB, b1f, b1i, b1c, b1o, c1b, h1oB);
        h1g[((0 * 4 + ch) * 8 + r2) * CSLAB + g * 512 + (1 * 16 + q * 4 + b) * 16 + ulz] = h1oB;
        wv_arrive(lc, fg, g, 1u, lane);
    }

    // ---- main loop: per wave, own chain only; no block-wide sync ----
#pragma unroll 1
    for (int i = 0; i < 79; ++i) {
        const int p_h2r = (i + 1) & 1, p_h1r = i & 1;
        const int p_h2w = i & 1, p_h1w = (i + 1) & 1;

        // pre-wait: x gather + x-partials of z1(i+1) for both m-tiles
        LOAD_X(0, i + 1);
        f32x4 acc1a = (f32x4){0.f, 0.f, 0.f, 0.f};
#pragma unroll
        for (int k2 = 0; k2 < 4; ++k2)
            acc1a = __builtin_amdgcn_mfma_f32_16x16x32_bf16(
                XFRAG(k2), as_bf16x8(*(const uint4*)(bp1 + (8 + k2) * 2048)), acc1a, 0, 0, 0);
        LOAD_X(1, i + 1);
        f32x4 acc1b = (f32x4){0.f, 0.f, 0.f, 0.f};
#pragma unroll
        for (int k2 = 0; k2 < 4; ++k2)
            acc1b = __builtin_amdgcn_mfma_f32_16x16x32_bf16(
                XFRAG(k2), as_bf16x8(*(const uint4*)(bp1 + (8 + k2) * 2048)), acc1b, 0, 0, 0);

        wv_wait(fg, (uint)(i + 1), lane);     // h2(i-1), h1(i) published

        __builtin_amdgcn_s_setprio(1);        // favor compute over sleeping pollers
        MSUB(0, acc1a, c1a, c2a, p_h2r, p_h1r, p_h2w, p_h1w);
        MSUB(1, acc1b, c1b, c2b, p_h2r, p_h1r, p_h2w, p_h1w);
        __builtin_amdgcn_s_setprio(0);

        wv_arrive(lc, fg, g, (uint)(i + 2), lane);   // publish h2(i), h1(i+1)
    }

    // ---- epilogue: z2(79) for both m-tiles ----
    {
        wv_wait(fg, 80u, lane);               // h2(78) par0, h1(79) par1
#pragma unroll 1
        for (int s = 0; s < 2; ++s) {
            const int m = s;
            const int loffm = (q >> 1) * 512 + (m * 16 + c16) * 16 + (q & 1) * 8;
            const int hidxm = g * 512 + (m * 16 + q * 4 + b) * 16 + ulz;
            const u16* h2b = h2g + ((0 * 4 + ch) * 8 + r2) * CSLAB + loffm;
            const u16* h1b = h1g + ((1 * 4 + ch) * 8 + r2) * CSLAB + loffm;
            u32x4 ag2[8], ag1[8];
#pragma unroll
            for (int ks = 0; ks < 8; ++ks) ag2[ks] = load_b128_sc0(h2b + ks * 1024);
#pragma unroll
            for (int ks = 0; ks < 8; ++ks) ag1[ks] = load_b128_sc0(h1b + ks * 1024);
            wait_vm0_fence_sched();
            f32x4 acc2 = (f32x4){0.f, 0.f, 0.f, 0.f};
#pragma unroll
            for (int ks = 0; ks < 8; ++ks)
                acc2 = __builtin_amdgcn_mfma_f32_16x16x32_bf16(
                    as_bf16x8v(ag2[ks]), as_bf16x8(*(const uint4*)(bp2 + ks * 2048)), acc2, 0, 0, 0);
#pragma unroll
            for (int ks = 0; ks < 8; ++ks)
                acc2 = __builtin_amdgcn_mfma_f32_16x16x32_bf16(
                    as_bf16x8v(ag1[ks]), as_bf16x8(*(const uint4*)(bp2 + (8 + ks) * 2048)), acc2, 0, 0, 0);
            u16 h2o;
            if (s == 0) { GATES(acc2, b2f, b2i, b2c, b2o, c2a, h2o); }
            else        { GATES(acc2, b2f, b2i, b2c, b2o, c2b, h2o); }
            h2g[((1 * 4 + ch) * 8 + r2) * CSLAB + hidxm] = h2o;   // h2(79) par1
        }
        wv_arrive(lc, fg, g, 81u, lane);
        wv_wait(fg, 81u, lane);
    }
    __syncthreads();   // join chains before output

    // ---- output: sigmoid(h2 @ w_out + b_out) by g==0 blocks ----
    if (g == 0) {
#pragma unroll 1
        for (int cc = 0; cc < 4; ++cc) {
            const u16* base = h2g + ((1 * 4 + cc) * 8 + r2) * CSLAB;
            int rr = tid >> 4, s = tid & 15;       // 32 rows x 16 unit-groups
            float dot = 0.f;
            if (tid < 512) {
                const u16* hp = base + s * 512 + rr * 16;
                u32x4 hv0 = load_b128_sc0(hp);
                u32x4 hv1 = load_b128_sc0(hp + 8);
                wait_vm0_fence_sched();
                const u16* wq = wob + s * 16;
                union { u32x4 v[2]; u16 h[16]; } hu; hu.v[0] = hv0; hu.v[1] = hv1;
#pragma unroll
                for (int k = 0; k < 16; ++k) dot += bf2f(hu.h[k]) * bf2f(wq[k]);
            }
            __syncthreads();
            if (tid < 512) outscr[rr * 16 + s] = dot;
            __syncthreads();
            if (tid < 32) {
                float ssum = 0.f;
                for (int k = 0; k < 16; ++k) ssum += outscr[tid * 16 + k];
                out[r2 * 128 + cc * 32 + tid] = fast_sigmoid(ssum + bf2f(bob[0]));
            }
        }
    }
}

extern "C" void kernel_launch(void* const* d_in, const int* in_sizes, int n_in,
                              void* d_out, int out_size, void* d_ws, size_t ws_size,
                              hipStream_t stream) {
    const int* tokens = (const int*)d_in[0];
    const void* emb = d_in[1];
    const void* wf1 = d_in[2];  const void* bf1_ = d_in[3];
    const void* wi1 = d_in[4];  const void* bi1_ = d_in[5];
    const void* wc1 = d_in[6];  const void* bc1_ = d_in[7];
    const void* wo1 = d_in[8];  const void* bo1_ = d_in[9];
    const void* wf2 = d_in[10]; const void* bf2_ = d_in[11];
    const void* wi2 = d_in[12]; const void* bi2_ = d_in[13];
    const void* wc2 = d_in[14]; const void* bc2_ = d_in[15];
    const void* wo2 = d_in[16]; const void* bo2_ = d_in[17];
    const void* w_out = d_in[18];
    const void* b_out = d_in[19];

    u16* wp1 = (u16*)d_ws;                 // 393216
    u16* wp2 = wp1 + 16 * 12 * 4 * 512;    // 524288
    u16* b1p = wp2 + 16 * 16 * 4 * 512;    // 1024
    u16* b2p = b1p + 1024;                 // 1024
    u16* wob = b2p + 1024;                 // 256
    u16* bob = wob + 256;                  // 8 (pad)
    u16* embp = bob + 8;                   // 1,000,000 (16B-aligned)
    u16* h1g = embp + 1000000;             // 2par x 4ch x 8rg x 8192 = 524288
    u16* h2g = h1g + 524288;               // same
    uint* flags = (uint*)(h2g + 524288);   // 4ch x 8rg x 64 uints = 2048

    pack_w<<<dim3(16 * 12), dim3(256), 0, stream>>>(wf1, wi1, wc1, wo1, bf1_, bi1_, bc1_, bo1_,
                                                    wp1, b1p, 356, 12);
    pack_w<<<dim3(16 * 16), dim3(256), 0, stream>>>(wf2, wi2, wc2, wo2, bf2_, bi2_, bc2_, bo2_,
                                                    wp2, b2p, 512, 16);
    pack_misc<<<dim3(512), dim3(256), 0, stream>>>(emb, w_out, b_out, embp, wob, bob, (uint*)h1g);
    lstm_kernel<<<dim3(128), dim3(1024), 0, stream>>>(tokens, embp, wp1, b1p, wp2, b2p,
                                                      wob, bob, h1g, h2g, flags, (float*)d_out);
}

// Round 17
// 766.337 us; speedup vs baseline: 1.1076x; 1.0018x over previous
//
#include <hip/hip_runtime.h>

typedef unsigned short u16;
typedef unsigned int uint;

using f32x4 = __attribute__((ext_vector_type(4))) float;
using bf16x8 = __attribute__((ext_vector_type(8))) __bf16;
using u32x4 = __attribute__((ext_vector_type(4))) uint;

static __device__ __forceinline__ bf16x8 as_bf16x8(uint4 u) {
    union { uint4 a; bf16x8 b; } c; c.a = u; return c.b;
}
static __device__ __forceinline__ bf16x8 as_bf16x8v(u32x4 u) {
    union { u32x4 a; bf16x8 b; } c; c.a = u; return c.b;
}
static __device__ __forceinline__ float bf2f(u16 h) {
    union { uint u; float f; } c; c.u = ((uint)h) << 16; return c.f;
}
static __device__ __forceinline__ u16 f2bf(float f) {
    union { float f; uint u; } c; c.f = f;
    uint u = c.u;
    return (u16)((u + 0x7fffu + ((u >> 16) & 1u)) >> 16);
}
static __device__ __forceinline__ float fast_sigmoid(float x) {
    x = fminf(30.f, fmaxf(-30.f, x));
    return __builtin_amdgcn_rcpf(1.0f + __builtin_amdgcn_exp2f(x * -1.44269504f));
}
static __device__ __forceinline__ float fast_tanh(float x) {
    x = fminf(15.f, fmaxf(-15.f, x));
    return 1.0f - 2.0f * __builtin_amdgcn_rcpf(1.0f + __builtin_amdgcn_exp2f(x * 2.88539008f));
}

static __device__ __forceinline__ u32x4 load_b128_sc0(const u16* p) {
    u32x4 r;
    asm volatile("global_load_dwordx4 %0, %1, off sc0" : "=v"(r) : "v"(p) : "memory");
    return r;
}
static __device__ __forceinline__ void wait_vm0_fence_sched() {
    asm volatile("s_waitcnt vmcnt(0)" ::: "memory");
    __builtin_amdgcn_sched_barrier(0);   // rule #18
}

// constant-index helpers (rule #20)
static __device__ __forceinline__ float vext(f32x4 v, int i) {
    float r = v[0];
    r = (i == 1) ? v[1] : r;
    r = (i == 2) ? v[2] : r;
    r = (i == 3) ? v[3] : r;
    return r;
}
static __device__ __forceinline__ float sel4(float a0, float a1, float a2, float a3, int i) {
    float r = a0;
    r = (i == 1) ? a1 : r;
    r = (i == 2) ? a2 : r;
    r = (i == 3) ? a3 : r;
    return r;
}

static __device__ __forceinline__ int detect_fp32(const uint* w, int nwords) {
    int hits = 0;
    for (int i = 0; i < nwords; ++i) { uint e = (w[i] >> 7) & 0xffu; hits += (e >= 0x80u); }
    return hits > (nwords >> 3);
}
static __device__ __forceinline__ u16 load_bf(const void* p, int i, int fp32) {
    return fp32 ? f2bf(((const float*)p)[i]) : ((const u16*)p)[i];
}

// Fragment-ordered weight pack: wp[((w*KSTEPS + ks)*4 + nt)*512 + lane*8 + j]
__global__ void pack_w(const void* wf, const void* wi, const void* wc, const void* wo,
                       const void* bbf, const void* bbi, const void* bbc, const void* bbo,
                       u16* __restrict__ wp, u16* __restrict__ bp, int K, int KSTEPS) {
    __shared__ int sfp;
    if (threadIdx.x == 0) sfp = detect_fp32((const uint*)wf, 256);
    __syncthreads();
    const int fp32 = sfp;
    int w = blockIdx.x / KSTEPS, ks = blockIdx.x % KSTEPS;
    int nt = threadIdx.x >> 6, lane = threadIdx.x & 63;
    int c16 = lane & 15, q = lane >> 4;
    int n = w * 64 + nt * 16 + c16;
    int u = n >> 2, g = n & 3;
    const void* W = (g == 0) ? wf : (g == 1) ? wi : (g == 2) ? wc : wo;
    union { u16 v[8]; uint4 u4; } tmp;
#pragma unroll
    for (int j = 0; j < 8; ++j) {
        int k = ks * 32 + q * 8 + j;
        tmp.v[j] = (k < K) ? load_bf(W, k * 256 + u, fp32) : (u16)0;
    }
    *(uint4*)(wp + ((w * KSTEPS + ks) * 4 + nt) * 512 + lane * 8) = tmp.u4;
    if (ks == 0 && threadIdx.x < 64) {
        int n2 = w * 64 + threadIdx.x;
        int g2 = n2 & 3;
        const void* B = (g2 == 0) ? bbf : (g2 == 1) ? bbi : (g2 == 2) ? bbc : bbo;
        bp[n2] = load_bf(B, n2 >> 2, fp32);
    }
}

__global__ void pack_misc(const void* emb, const void* w_out, const void* b_out,
                          u16* __restrict__ embp, u16* __restrict__ wob,
                          u16* __restrict__ bob, uint* __restrict__ hzero) {
    __shared__ int sfp;
    if (threadIdx.x == 0) sfp = detect_fp32((const uint*)emb, 256);
    __syncthreads();
    const int fp32 = sfp;
    int gid = blockIdx.x * blockDim.x + threadIdx.x;
    int stride = gridDim.x * blockDim.x;
    for (int i = gid; i < 1000000; i += stride)
        embp[i] = load_bf(emb, i, fp32);
    // zero h1g+h2g (524288 uints) + flags (4ch x 8rg x 64 = 2048 uints)
    for (int i = gid; i < 526336; i += stride) hzero[i] = 0;
    if (blockIdx.x == 0) {
        __shared__ int sfp2;
        if (threadIdx.x == 0) sfp2 = detect_fp32((const uint*)w_out, 128);
        __syncthreads();
        if (threadIdx.x < 256) wob[threadIdx.x] = load_bf(w_out, threadIdx.x, sfp2);
        if (threadIdx.x == 0) bob[0] = load_bf(b_out, 0, sfp2);
    }
}

// Chain wait, DESIGNATED-POLLER form: only ONE wave per chain per block polls
// the global flag line (one coalesced 64B sc0 request per poll, s_sleep
// backoff, LLC-atomic safety net — cannot hang). It then releases its chain's
// other waves through an LDS word; they poll LDS only (zero L2 traffic).
// Cuts same-line L2 pollers 4x (256 -> 64 waves/XCD), de-contending both the
// flag lines and the co-resident h-data loads.
static __device__ __forceinline__ void chain_wait(uint* grp, uint* lrel_ch,
                                                  uint phase, int lane, bool poller) {
    if (poller) {
        const uint* fp = grp + (lane & 15);
        uint* cnt = grp + 32;
        int k = 0;
        while (true) {
            uint v;
            asm volatile("global_load_dword %0, %1, off sc0\n\t"
                         "s_waitcnt vmcnt(0)"
                         : "=v"(v) : "v"(fp) : "memory");
            if (__all((int)(v >= phase))) break;
            __builtin_amdgcn_s_sleep(2);
            if (((++k) & 7) == 0 &&
                __hip_atomic_load(cnt, __ATOMIC_RELAXED,
                                  __HIP_MEMORY_SCOPE_AGENT) >= 16u * phase)
                break;
        }
        __hip_atomic_store(lrel_ch, phase, __ATOMIC_RELAXED,
                           __HIP_MEMORY_SCOPE_WORKGROUP);
    } else {
        while (__hip_atomic_load(lrel_ch, __ATOMIC_RELAXED,
                                 __HIP_MEMORY_SCOPE_WORKGROUP) < phase)
            __builtin_amdgcn_s_sleep(2);
    }
}

// Per-WAVE arrive: drain own stores (vmcnt per-wave), bump LDS counter; the
// LAST of the chain's 4 waves publishes the flag (sc0) + LLC safety add.
static __device__ __forceinline__ void wv_arrive(uint* ldsc_ch, uint* grp, int g,
                                                 uint phase, int lane) {
    asm volatile("s_waitcnt vmcnt(0)" ::: "memory");
    if (lane == 0) {
        uint old = __hip_atomic_fetch_add(ldsc_ch, 1u, __ATOMIC_RELAXED,
                                          __HIP_MEMORY_SCOPE_WORKGROUP);
        if (old == 4u * phase - 1u) {            // last of the 4 waves
            uint* slot = grp + g;
            asm volatile("global_store_dword %0, %1, off sc0"
                         :: "v"(slot), "v"(phase) : "memory");
            __hip_atomic_fetch_add(grp + 32, 1u, __ATOMIC_RELAXED,
                                   __HIP_MEMORY_SCOPE_AGENT);
        }
    }
}

// Persistent-weight LSTM, FOUR wave-specialized chains, designated-poller
// flag waits (R16 + poller/LDS-release). chain = wv>>2: each SIMD hosts one
// wave of each chain. Zero block-wide barriers in the main loop.
// Grid 128 = 8 row-groups (bid&7, XCD-affine) x 16 unit-groups.
// h layout block-major: h[par][ch][rg][g][row:32][ul:16].
#define CSLAB 8192

__global__ void __launch_bounds__(1024, 1)
lstm_kernel(const int* __restrict__ tokens, const u16* __restrict__ embp,
            const u16* __restrict__ wp1, const u16* __restrict__ b1p,
            const u16* __restrict__ wp2, const u16* __restrict__ b2p,
            const u16* __restrict__ wob, const u16* __restrict__ bob,
            u16* __restrict__ h1g, u16* __restrict__ h2g,
            uint* __restrict__ flags, float* __restrict__ out) {
    __shared__ __align__(16) u16 w1s[12 * 4 * 512];   // 49152 B
    __shared__ __align__(16) u16 w2s[16 * 4 * 512];   // 65536 B
    __shared__ uint ldsc[4];                          // per-chain arrival counters
    __shared__ uint lrel[4];                          // per-chain LDS release words
    __shared__ __align__(16) float outscr[512];       // 2048 B (epilogue)

    const int tid = threadIdx.x;
    const int bid = blockIdx.x;
    const int r2 = bid & 7;                 // row-group (XCD-affine)
    const int g = bid >> 3;                 // unit-group 0..15
    const int lane = tid & 63;
    const int wv = tid >> 6;                // 0..15
    const int ch = wv >> 2;                 // chain 0..3 (one wave per SIMD each)
    const int nt = wv & 3;                  // n-tile
    const bool poller = (nt == 0);          // designated flag poller of the chain
    const int c16 = lane & 15, q = lane >> 4;

    const int b = lane & 3;
    const int ulz = nt * 4 + ((lane & 15) >> 2);
    const int gunit = g * 16 + ulz;

    {
        const uint4* s1 = (const uint4*)(wp1 + g * (12 * 4 * 512));
        uint4* d1 = (uint4*)w1s;
        for (int i = tid; i < 3072; i += 1024) d1[i] = s1[i];
        const uint4* s2 = (const uint4*)(wp2 + g * (16 * 4 * 512));
        uint4* d2 = (uint4*)w2s;
        for (int i = tid; i < 4096; i += 1024) d2[i] = s2[i];
        if (tid < 4) { ldsc[tid] = 0u; lrel[tid] = 0u; }
    }
    ushort4 bl1 = *(const ushort4*)(b1p + gunit * 4);
    ushort4 bl2 = *(const ushort4*)(b2p + gunit * 4);
    const float b1f = bf2f(bl1.x), b1i = bf2f(bl1.y), b1c = bf2f(bl1.z), b1o = bf2f(bl1.w);
    const float b2f = bf2f(bl2.x), b2i = bf2f(bl2.y), b2c = bf2f(bl2.z), b2o = bf2f(bl2.w);
    float c1a = 0.f, c1b = 0.f, c2a = 0.f, c2b = 0.f;   // m0/m1 cell states
    uint* fg = flags + (ch * 8 + r2) * 64;
    uint* lc = &ldsc[ch];
    uint* lr = &lrel[ch];
    __syncthreads();                        // weights + counters ready

    const u16* bp1 = w1s + nt * 512 + lane * 8;
    const u16* bp2 = w2s + nt * 512 + lane * 8;

    ushort4 xlo[4], xhi[4];
#define LOAD_X(m, t)                                                           \
    {                                                                          \
        int row = r2 * 128 + ch * 32 + (m) * 16 + c16;                         \
        int tok = tokens[row * 80 + (t)];                                      \
        const u16* xb = embp + tok * 100 + q * 8;                              \
        _Pragma("unroll")                                                      \
        for (int k2 = 0; k2 < 4; ++k2) {                                       \
            xlo[k2] = *(const ushort4*)(xb + k2 * 32);                         \
            xhi[k2] = *(const ushort4*)(xb + k2 * 32 + 4);                     \
        }                                                                      \
    }
#define XFRAG(k2) ({ union { ushort4 a[2]; bf16x8 v; } xu;                     \
                     xu.a[0] = xlo[k2]; xu.a[1] = xhi[k2]; xu.v; })

#define GATES(accv, B0, B1, B2, B3, cref, hout)                                \
    {                                                                          \
        float v0 = vext(accv, b);                                              \
        float v1 = __shfl_xor(vext(accv, b ^ 1), 1, 64);                       \
        float v2 = __shfl_xor(vext(accv, b ^ 2), 2, 64);                       \
        float v3 = __shfl_xor(vext(accv, b ^ 3), 3, 64);                       \
        float zf = sel4(v0, v1, v2, v3, b);                                    \
        float zi = sel4(v0, v1, v2, v3, b ^ 1);                                \
        float zc = sel4(v0, v1, v2, v3, b ^ 2);                                \
        float zo = sel4(v0, v1, v2, v3, b ^ 3);                                \
        float gf = fast_sigmoid(zf + B0);                                      \
        float gi = fast_sigmoid(zi + B1);                                      \
        float gc = fast_tanh(zc + B2);                                         \
        float go = fast_sigmoid(zo + B3);                                      \
        float cn = gf * cref + gi * gc;                                        \
        cref = cn;                                                             \
        hout = f2bf(go * fast_tanh(cn));                                       \
    }

// one m-sub of one chain-step: z2(i) (K=512) + finish z1(i+1) (h1-part),
// gates, scattered u16 stores. acc1 carries the pre-wait x-partial.
#define MSUB(m, acc1, c1ref, c2ref, p2r, p1r, p2w, p1w)                        \
    {                                                                          \
        const int loffm = (q >> 1) * 512 + ((m) * 16 + c16) * 16 + (q & 1) * 8; \
        const int hidxm = g * 512 + ((m) * 16 + q * 4 + b) * 16 + ulz;         \
        const u16* h2b = h2g + (((p2r) * 4 + ch) * 8 + r2) * CSLAB + loffm;    \
        const u16* h1b = h1g + (((p1r) * 4 + ch) * 8 + r2) * CSLAB + loffm;    \
        u32x4 ag2[8], ag1[8];                                                  \
        _Pragma("unroll")                                                      \
        for (int ks = 0; ks < 8; ++ks) ag2[ks] = load_b128_sc0(h2b + ks * 1024); \
        _Pragma("unroll")                                                      \
        for (int ks = 0; ks < 8; ++ks) ag1[ks] = load_b128_sc0(h1b + ks * 1024); \
        wait_vm0_fence_sched();                                                \
        f32x4 acc2 = (f32x4){0.f, 0.f, 0.f, 0.f};                              \
        _Pragma("unroll")                                                      \
        for (int ks = 0; ks < 8; ++ks)                                         \
            acc2 = __builtin_amdgcn_mfma_f32_16x16x32_bf16(                    \
                as_bf16x8v(ag2[ks]), as_bf16x8(*(const uint4*)(bp2 + ks * 2048)), acc2, 0, 0, 0); \
        _Pragma("unroll")                                                      \
        for (int ks = 0; ks < 8; ++ks)                                         \
            acc2 = __builtin_amdgcn_mfma_f32_16x16x32_bf16(                    \
                as_bf16x8v(ag1[ks]), as_bf16x8(*(const uint4*)(bp2 + (8 + ks) * 2048)), acc2, 0, 0, 0); \
        _Pragma("unroll")                                                      \
        for (int ks = 0; ks < 8; ++ks)                                         \
            acc1 = __builtin_amdgcn_mfma_f32_16x16x32_bf16(                    \
                as_bf16x8v(ag1[ks]), as_bf16x8(*(const uint4*)(bp1 + ks * 2048)), acc1, 0, 0, 0); \
        u16 h2o, h1o;                                                          \
        GATES(acc2, b2f, b2i, b2c, b2o, c2ref, h2o);                           \
        GATES(acc1, b1f, b1i, b1c, b1o, c1ref, h1o);                           \
        h2g[(((p2w) * 4 + ch) * 8 + r2) * CSLAB + hidxm] = h2o;                \
        h1g[(((p1w) * 4 + ch) * 8 + r2) * CSLAB + hidxm] = h1o;                \
    }

    // ---- prologue: h1(0) (x-only) for both m-tiles, publish phase 1 ----
    {
        LOAD_X(0, 0);
        f32x4 acc = (f32x4){0.f, 0.f, 0.f, 0.f};
#pragma unroll
        for (int k2 = 0; k2 < 4; ++k2)
            acc = __builtin_amdgcn_mfma_f32_16x16x32_bf16(
                XFRAG(k2), as_bf16x8(*(const uint4*)(bp1 + (8 + k2) * 2048)), acc, 0, 0, 0);
        u16 h1o;
        GATES(acc, b1f, b1i, b1c, b1o, c1a, h1o);
        h1g[((0 * 4 + ch) * 8 + r2) * CSLAB + g * 512 + (0 * 16 + q * 4 + b) * 16 + ulz] = h1o;
        LOAD_X(1, 0);
        f32x4 accB = (f32x4){0.f, 0.f, 0.f, 0.f};
#pragma unroll
        for (int k2 = 0; k2 < 4; ++k2)
            accB = __builtin_amdgcn_mfma_f32_16x16x32_bf16(
                XFRAG(k2), as_bf16x8(*(const uint4*)(bp1 + (8 + k2) * 2048)), accB, 0, 0, 0);
        u16 h1oB;
        GATES(accB, b1f, b1i, b1c, b1o, c1b, h1oB);
        h1g[((0 * 4 + ch) * 8 + r2) * CSLAB + g * 512 + (1 * 16 + q * 4 + b) * 16 + ulz] = h1oB;
        wv_arrive(lc, fg, g, 1u, lane);
    }

    // ---- main loop: per wave, own chain only; no block-wide sync ----
#pragma unroll 1
    for (int i = 0; i < 79; ++i) {
        const int p_h2r = (i + 1) & 1, p_h1r = i & 1;
        const int p_h2w = i & 1, p_h1w = (i + 1) & 1;

        // pre-wait: x gather + x-partials of z1(i+1) for both m-tiles
        LOAD_X(0, i + 1);
        f32x4 acc1a = (f32x4){0.f, 0.f, 0.f, 0.f};
#pragma unroll
        for (int k2 = 0; k2 < 4; ++k2)
            acc1a = __builtin_amdgcn_mfma_f32_16x16x32_bf16(
                XFRAG(k2), as_bf16x8(*(const uint4*)(bp1 + (8 + k2) * 2048)), acc1a, 0, 0, 0);
        LOAD_X(1, i + 1);
        f32x4 acc1b = (f32x4){0.f, 0.f, 0.f, 0.f};
#pragma unroll
        for (int k2 = 0; k2 < 4; ++k2)
            acc1b = __builtin_amdgcn_mfma_f32_16x16x32_bf16(
                XFRAG(k2), as_bf16x8(*(const uint4*)(bp1 + (8 + k2) * 2048)), acc1b, 0, 0, 0);

        chain_wait(fg, lr, (uint)(i + 1), lane, poller);  // h2(i-1), h1(i) ready

        __builtin_amdgcn_s_setprio(1);        // favor compute over sleeping pollers
        MSUB(0, acc1a, c1a, c2a, p_h2r, p_h1r, p_h2w, p_h1w);
        MSUB(1, acc1b, c1b, c2b, p_h2r, p_h1r, p_h2w, p_h1w);
        __builtin_amdgcn_s_setprio(0);

        wv_arrive(lc, fg, g, (uint)(i + 2), lane);   // publish h2(i), h1(i+1)
    }

    // ---- epilogue: z2(79) for both m-tiles ----
    {
        chain_wait(fg, lr, 80u, lane, poller);   // h2(78) par0, h1(79) par1
#pragma unroll 1
        for (int s = 0; s < 2; ++s) {
            const int m = s;
            const int loffm = (q >> 1) * 512 + (m * 16 + c16) * 16 + (q & 1) * 8;
            const int hidxm = g * 512 + (m * 16 + q * 4 + b) * 16 + ulz;
            const u16* h2b = h2g + ((0 * 4 + ch) * 8 + r2) * CSLAB + loffm;
            const u16* h1b = h1g + ((1 * 4 + ch) * 8 + r2) * CSLAB + loffm;
            u32x4 ag2[8], ag1[8];
#pragma unroll
            for (int ks = 0; ks < 8; ++ks) ag2[ks] = load_b128_sc0(h2b + ks * 1024);
#pragma unroll
            for (int ks = 0; ks < 8; ++ks) ag1[ks] = load_b128_sc0(h1b + ks * 1024);
            wait_vm0_fence_sched();
            f32x4 acc2 = (f32x4){0.f, 0.f, 0.f, 0.f};
#pragma unroll
            for (int ks = 0; ks < 8; ++ks)
                acc2 = __builtin_amdgcn_mfma_f32_16x16x32_bf16(
                    as_bf16x8v(ag2[ks]), as_bf16x8(*(const uint4*)(bp2 + ks * 2048)), acc2, 0, 0, 0);
#pragma unroll
            for (int ks = 0; ks < 8; ++ks)
                acc2 = __builtin_amdgcn_mfma_f32_16x16x32_bf16(
                    as_bf16x8v(ag1[ks]), as_bf16x8(*(const uint4*)(bp2 + (8 + ks) * 2048)), acc2, 0, 0, 0);
            u16 h2o;
            if (s == 0) { GATES(acc2, b2f, b2i, b2c, b2o, c2a, h2o); }
            else        { GATES(acc2, b2f, b2i, b2c, b2o, c2b, h2o); }
            h2g[((1 * 4 + ch) * 8 + r2) * CSLAB + hidxm] = h2o;   // h2(79) par1
        }
        wv_arrive(lc, fg, g, 81u, lane);
        chain_wait(fg, lr, 81u, lane, poller);
    }
    __syncthreads();   // join chains before output

    // ---- output: sigmoid(h2 @ w_out + b_out) by g==0 blocks ----
    if (g == 0) {
#pragma unroll 1
        for (int cc = 0; cc < 4; ++cc) {
            const u16* base = h2g + ((1 * 4 + cc) * 8 + r2) * CSLAB;
            int rr = tid >> 4, s = tid & 15;       // 32 rows x 16 unit-groups
            float dot = 0.f;
            if (tid < 512) {
                const u16* hp = base + s * 512 + rr * 16;
                u32x4 hv0 = load_b128_sc0(hp);
                u32x4 hv1 = load_b128_sc0(hp + 8);
                wait_vm0_fence_sched();
                const u16* wq = wob + s * 16;
                union { u32x4 v[2]; u16 h[16]; } hu; hu.v[0] = hv0; hu.v[1] = hv1;
#pragma unroll
                for (int k = 0; k < 16; ++k) dot += bf2f(hu.h[k]) * bf2f(wq[k]);
            }
            __syncthreads();
            if (tid < 512) outscr[rr * 16 + s] = dot;
            __syncthreads();
            if (tid < 32) {
                float ssum = 0.f;
                for (int k = 0; k < 16; ++k) ssum += outscr[tid * 16 + k];
                out[r2 * 128 + cc * 32 + tid] = fast_sigmoid(ssum + bf2f(bob[0]));
            }
        }
    }
}

extern "C" void kernel_launch(void* const* d_in, const int* in_sizes, int n_in,
                              void* d_out, int out_size, void* d_ws, size_t ws_size,
                              hipStream_t stream) {
    const int* tokens = (const int*)d_in[0];
    const void* emb = d_in[1];
    const void* wf1 = d_in[2];  const void* bf1_ = d_in[3];
    const void* wi1 = d_in[4];  const void* bi1_ = d_in[5];
    const void* wc1 = d_in[6];  const void* bc1_ = d_in[7];
    const void* wo1 = d_in[8];  const void* bo1_ = d_in[9];
    const void* wf2 = d_in[10]; const void* bf2_ = d_in[11];
    const void* wi2 = d_in[12]; const void* bi2_ = d_in[13];
    const void* wc2 = d_in[14]; const void* bc2_ = d_in[15];
    const void* wo2 = d_in[16]; const void* bo2_ = d_in[17];
    const void* w_out = d_in[18];
    const void* b_out = d_in[19];

    u16* wp1 = (u16*)d_ws;                 // 393216
    u16* wp2 = wp1 + 16 * 12 * 4 * 512;    // 524288
    u16* b1p = wp2 + 16 * 16 * 4 * 512;    // 1024
    u16* b2p = b1p + 1024;                 // 1024
    u16* wob = b2p + 1024;                 // 256
    u16* bob = wob + 256;                  // 8 (pad)
    u16* embp = bob + 8;                   // 1,000,000 (16B-aligned)
    u16* h1g = embp + 1000000;             // 2par x 4ch x 8rg x 8192 = 524288
    u16* h2g = h1g + 524288;               // same
    uint* flags = (uint*)(h2g + 524288);   // 4ch x 8rg x 64 uints = 2048

    pack_w<<<dim3(16 * 12), dim3(256), 0, stream>>>(wf1, wi1, wc1, wo1, bf1_, bi1_, bc1_, bo1_,
                                                    wp1, b1p, 356, 12);
    pack_w<<<dim3(16 * 16), dim3(256), 0, stream>>>(wf2, wi2, wc2, wo2, bf2_, bi2_, bc2_, bo2_,
                                                    wp2, b2p, 512, 16);
    pack_misc<<<dim3(512), dim3(256), 0, stream>>>(emb, w_out, b_out, embp, wob, bob, (uint*)h1g);
    lstm_kernel<<<dim3(128), dim3(1024), 0, stream>>>(tokens, embp, wp1, b1p, wp2, b2p,
                                                      wob, bob, h1g, h2g, flags, (float*)d_out);
}